// Round 11
// baseline (141.007 us; speedup 1.0000x reference)
//
#include <hip/hip_runtime.h>
#include <hip/hip_bf16.h>

// S=8192, D_IN=512, D_OUT=64. O = softmax(tril(QK^T)/8) @ V.
// Round 11 (= R10 + compile fix): proj rebuilt as staged GEMM (x read once,
// coalesced, all 3 mats per block via 24KB W-tile + 8KB x-tile in swizzled
// LDS, global_load_lds). cast kernel for x+W -> bf16. attn + reduce
// byte-exact from R9 (validated). Fix: nt store uses native u32x2 vector.

typedef __attribute__((ext_vector_type(8))) short short8;   // 8 bf16 MFMA A/B frag
typedef __attribute__((ext_vector_type(4))) float f32x4;    // MFMA C/D frag
typedef __attribute__((ext_vector_type(4))) float f4v;
typedef __attribute__((ext_vector_type(2))) unsigned int u32x2;  // native, nt-store-legal

__device__ inline unsigned short bf16u(float a) {
    union { __hip_bfloat16 h; unsigned short u; } v;
    v.h = __float2bfloat16(a);
    return v.u;
}
__device__ inline unsigned int pk2(float a, float b) {
    union { __hip_bfloat162 h; unsigned int u; } v;
    v.h = __float22bfloat162_rn(make_float2(a, b));
    return v.u;
}
__device__ inline void gload_lds16(const void* g, void* l) {
    __builtin_amdgcn_global_load_lds(
        (const __attribute__((address_space(1))) unsigned int*)g,
        (__attribute__((address_space(3))) unsigned int*)l, 16, 0, 0);
}

// Q-blocks of 128 rows, parts of 512 cols: np(qb) = (qb>>2)+1.
// base(qb) = qb + 2g(g-1) + (qb&3)*g, g = qb>>2. Total slots = 544.
__device__ inline int part_base(int qb) {
    int g = qb >> 2;
    return qb + 2 * g * (g - 1) + (qb & 3) * g;
}

// ---------------- cast x + W (fp32 -> bf16), one dispatch ----------------
// blocks 0..4095: x (1,048,576 float4). blocks 4096..4191: W (24,576 float4).
__global__ __launch_bounds__(256) void cast_kernel(const float* __restrict__ x,
                                                   const float* __restrict__ wq,
                                                   const float* __restrict__ wk,
                                                   const float* __restrict__ wv,
                                                   unsigned short* __restrict__ xb,
                                                   unsigned short* __restrict__ wb) {
    const int b = blockIdx.x;
    if (b < 4096) {
        const int i = b * 256 + threadIdx.x;
        f4v v = __builtin_nontemporal_load((const f4v*)x + i);
        u32x2 o;
        o.x = pk2(v.x, v.y);
        o.y = pk2(v.z, v.w);
        __builtin_nontemporal_store(o, (u32x2*)xb + i);
    } else {
        const int j = (b - 4096) * 256 + threadIdx.x;   // < 24576
        const int mat = j >> 13, idx = j & 8191;
        const float* src = (mat == 0) ? wq : ((mat == 1) ? wk : wv);
        f4v v = __builtin_nontemporal_load((const f4v*)src + idx);
        u32x2 o;
        o.x = pk2(v.x, v.y);
        o.y = pk2(v.z, v.w);
        *((u32x2*)(wb + mat * 32768) + idx) = o;
    }
}

// ---------------- proj: staged GEMM [8192,512]x[512,192], x read once ----------------
// grid 128, 256 thr (4 waves, 16 rows each). 8 K-chunks of 64.
// LDS: x-tile [64][64] 8KB + W-tile [192][64] 24KB, both chunk^=(row&7).
__global__ __launch_bounds__(256) void proj_kernel(const unsigned short* __restrict__ xb,
                                                   const unsigned short* __restrict__ wb,
                                                   unsigned short* __restrict__ qb,
                                                   unsigned short* __restrict__ kb,
                                                   unsigned short* __restrict__ vt) {
    __shared__ unsigned short lds_x[64 * 64];    // 8 KB
    __shared__ unsigned short lds_w[192 * 64];   // 24 KB
    const int tid = threadIdx.x;
    const int wave = tid >> 6, lane = tid & 63;
    const int l16 = lane & 15, quad = lane >> 4;
    const int r0 = blockIdx.x * 64;

    f32x4 acc[12] = {};                          // ng 0..11 (n = ng*16+l16, 192 outs)

    for (int kc = 0; kc < 8; ++kc) {
        const int k0 = kc * 64;
        // stage x-tile: 512 chunks, 2 per thread
#pragma unroll
        for (int s = 0; s < 2; ++s) {
            const int idx = s * 256 + tid;
            const int row = idx >> 3;
            const int cc = (idx & 7) ^ (row & 7);
            gload_lds16(xb + (r0 + row) * 512 + k0 + cc * 8, lds_x + idx * 8);
        }
        // stage W-tile: 1536 chunks, 6 per thread (rows n = 0..191)
#pragma unroll
        for (int s = 0; s < 6; ++s) {
            const int idx = s * 256 + tid;
            const int row = idx >> 3;
            const int cc = (idx & 7) ^ (row & 7);
            gload_lds16(wb + row * 512 + k0 + cc * 8, lds_w + idx * 8);
        }
        __syncthreads();

        // A-frags: x[wave*16+l16][kg*32+quad*8..]
        short8 af[2];
#pragma unroll
        for (int kg = 0; kg < 2; ++kg)
            af[kg] = *(const short8*)(lds_x + (wave * 16 + l16) * 64 +
                                      (((kg * 4 + quad) ^ (l16 & 7)) * 8));
#pragma unroll
        for (int ng = 0; ng < 12; ++ng) {
            short8 vf0 = *(const short8*)(lds_w + (ng * 16 + l16) * 64 +
                                          (((0 * 4 + quad) ^ (l16 & 7)) * 8));
            short8 vf1 = *(const short8*)(lds_w + (ng * 16 + l16) * 64 +
                                          (((1 * 4 + quad) ^ (l16 & 7)) * 8));
            acc[ng] = __builtin_amdgcn_mfma_f32_16x16x32_bf16(af[0], vf0, acc[ng], 0, 0, 0);
            acc[ng] = __builtin_amdgcn_mfma_f32_16x16x32_bf16(af[1], vf1, acc[ng], 0, 0, 0);
        }
        __syncthreads();
    }

    // epilogue: D[m=quad*4+r][n=l16] ; n_global = ng*16+l16; mat = ng>>2 (uniform)
#pragma unroll
    for (int ng = 0; ng < 12; ++ng) {
        const int mat = ng >> 2;
        const int colm = (ng & 3) * 16 + l16;    // 0..63 within mat
        const float scale = (mat == 0) ? 0.125f : 1.0f;
#pragma unroll
        for (int r = 0; r < 4; ++r) {
            const int row = r0 + wave * 16 + quad * 4 + r;
            const unsigned short hv = bf16u(acc[ng][r] * scale);
            if (mat == 0)       qb[row * 64 + colm] = hv;
            else if (mat == 1)  kb[row * 64 + colm] = hv;
            else                vt[colm * 8192 + row] = hv;   // V^T [64][8192]
        }
    }
}

// ---------------- staged split-K flash attention (R6/R9 byte-exact) ----------------
// grid (16, 64), 256 thr. blockIdx.y = qb (128 Q rows), x = part (512 cols).
__global__ __launch_bounds__(256) void attn_kernel(const unsigned short* __restrict__ qbuf,
                                                   const unsigned short* __restrict__ kbuf,
                                                   const unsigned short* __restrict__ vt,
                                                   float* __restrict__ O_part,
                                                   float* __restrict__ l_part) {
    const int qb_i = blockIdx.y;
    const int part = blockIdx.x;
    const int g = qb_i >> 2;
    if (part > g) return;                         // np = g+1; block-uniform exit

    __shared__ unsigned short lds_k[64 * 64];     // [row][64], chunk^=(row&7)
    __shared__ unsigned short lds_v[64 * 64];     // V^T tile [dim][64], chunk^=(dim&7)
    __shared__ unsigned short lds_p[4][32 * 72];  // per-wave P, stride 72

    const int tid = threadIdx.x;
    const int wave = tid >> 6, lane = tid & 63;
    const int l16 = lane & 15, quad = lane >> 4;
    const int q0 = qb_i * 128;
    const int q0w = q0 + wave * 32;
    const int c0 = part * 512;
    const int cend = min(c0 + 512, q0 + 128);     // 64-aligned
    const int ntiles = (cend - c0) >> 6;
    unsigned short* lp = lds_p[wave];

    f32x4 o[2][4] = {};
    float ls[2] = {0.f, 0.f};

    short8 qf[2][2];
#pragma unroll
    for (int cg = 0; cg < 2; ++cg)
#pragma unroll
        for (int kg = 0; kg < 2; ++kg)
            qf[cg][kg] = *(const short8*)(qbuf + (q0w + cg * 16 + l16) * 64 + kg * 32 + quad * 8);

    for (int it = 0; it < ntiles; ++it) {
        const int kc0 = c0 + it * 64;
#pragma unroll
        for (int s = 0; s < 2; ++s) {
            const int idx = (wave * 2 + s) * 64 + lane;   // 0..511
            const int srow = idx >> 3;
            const int scc = (idx & 7) ^ (srow & 7);
            gload_lds16(kbuf + (kc0 + srow) * 64 + scc * 8, lds_k + idx * 8);
            gload_lds16(vt + srow * 8192 + kc0 + scc * 8,   lds_v + idx * 8);
        }
        __syncthreads();

        if (kc0 <= q0w + 31) {
            short8 af[4][2], vf[4][2];
#pragma unroll
            for (int rg = 0; rg < 4; ++rg)
#pragma unroll
                for (int kg = 0; kg < 2; ++kg)
                    af[rg][kg] = *(const short8*)(lds_k + (rg * 16 + l16) * 64 +
                                                  (((kg * 4 + quad) ^ (l16 & 7)) * 8));
#pragma unroll
            for (int ng = 0; ng < 4; ++ng)
#pragma unroll
                for (int kg = 0; kg < 2; ++kg)
                    vf[ng][kg] = *(const short8*)(lds_v + (ng * 16 + l16) * 64 +
                                                  (((kg * 4 + quad) ^ (l16 & 7)) * 8));

            f32x4 st[4][2];
#pragma unroll
            for (int rg = 0; rg < 4; ++rg)
#pragma unroll
                for (int cg = 0; cg < 2; ++cg) {
                    f32x4 z = {};
                    z          = __builtin_amdgcn_mfma_f32_16x16x32_bf16(af[rg][0], qf[cg][0], z, 0, 0, 0);
                    st[rg][cg] = __builtin_amdgcn_mfma_f32_16x16x32_bf16(af[rg][1], qf[cg][1], z, 0, 0, 0);
                }

            if (kc0 + 63 > q0w) {
#pragma unroll
                for (int rg = 0; rg < 4; ++rg)
#pragma unroll
                    for (int cg = 0; cg < 2; ++cg)
#pragma unroll
                        for (int r = 0; r < 4; ++r) {
                            const int kcol = kc0 + rg * 16 + quad * 4 + r;
                            const int qrow = q0w + cg * 16 + l16;
                            if (kcol > qrow) st[rg][cg][r] = -3.0e38f;
                        }
            }

#pragma unroll
            for (int rg = 0; rg < 4; ++rg)
#pragma unroll
                for (int cg = 0; cg < 2; ++cg)
#pragma unroll
                    for (int r = 0; r < 4; ++r) {
                        const float p = __expf(st[rg][cg][r]);
                        st[rg][cg][r] = p;
                        ls[cg] += p;
                    }

#pragma unroll
            for (int rg = 0; rg < 4; ++rg)
#pragma unroll
                for (int cg = 0; cg < 2; ++cg) {
                    u32x2 w;
                    w.x = pk2(st[rg][cg][0], st[rg][cg][1]);
                    w.y = pk2(st[rg][cg][2], st[rg][cg][3]);
                    *(u32x2*)(lp + (cg * 16 + l16) * 72 + rg * 16 + quad * 4) = w;
                }
            asm volatile("s_waitcnt lgkmcnt(0)" ::: "memory");
            short8 pa[2][2];
#pragma unroll
            for (int mg = 0; mg < 2; ++mg)
#pragma unroll
                for (int kg = 0; kg < 2; ++kg)
                    pa[mg][kg] = *(const short8*)(lp + (mg * 16 + l16) * 72 + kg * 32 + quad * 8);

#pragma unroll
            for (int mg = 0; mg < 2; ++mg)
#pragma unroll
                for (int ng = 0; ng < 4; ++ng) {
                    o[mg][ng] = __builtin_amdgcn_mfma_f32_16x16x32_bf16(pa[mg][0], vf[ng][0], o[mg][ng], 0, 0, 0);
                    o[mg][ng] = __builtin_amdgcn_mfma_f32_16x16x32_bf16(pa[mg][1], vf[ng][1], o[mg][ng], 0, 0, 0);
                }
        }
        __syncthreads();
    }

#pragma unroll
    for (int cg = 0; cg < 2; ++cg) {
        ls[cg] += __shfl_xor(ls[cg], 16, 64);
        ls[cg] += __shfl_xor(ls[cg], 32, 64);
    }

    const int slot = part_base(qb_i) + part;
    float* Op = O_part + (size_t)slot * 8192;
#pragma unroll
    for (int mg = 0; mg < 2; ++mg)
#pragma unroll
        for (int ng = 0; ng < 4; ++ng)
#pragma unroll
            for (int r = 0; r < 4; ++r)
                __builtin_nontemporal_store(o[mg][ng][r],
                    Op + (wave * 32 + mg * 16 + quad * 4 + r) * 64 + ng * 16 + l16);
    if (quad == 0) {
#pragma unroll
        for (int cg = 0; cg < 2; ++cg)
            __builtin_nontemporal_store(ls[cg],
                l_part + slot * 128 + wave * 32 + cg * 16 + l16);
    }
}

// ---------------- combine: sum partials, normalize (R6/R9 byte-exact) ----------------
__global__ __launch_bounds__(256) void attn_reduce_kernel(const float* __restrict__ O_part,
                                                          const float* __restrict__ l_part,
                                                          float* __restrict__ out) {
    __shared__ float Ls[32];
    const int qb_i = blockIdx.x >> 2;
    const int q4 = blockIdx.x & 3;
    const int t = threadIdx.x;
    const int np = (qb_i >> 2) + 1;
    const int base = part_base(qb_i);

    if (t < 32) {
        float s = 0.0f;
        for (int p = 0; p < np; ++p)
            s += __builtin_nontemporal_load(l_part + (base + p) * 128 + q4 * 32 + t);
        Ls[t] = s;
    }
    __syncthreads();

#pragma unroll
    for (int u = 0; u < 2; ++u) {
        const int e = q4 * 2048 + (t * 2 + u) * 4;
        const int row = (t * 2 + u) >> 4;
        f4v acc = {0.f, 0.f, 0.f, 0.f};
        for (int p = 0; p < np; ++p)
            acc += __builtin_nontemporal_load((const f4v*)(O_part + (size_t)(base + p) * 8192 + e));
        acc *= (1.0f / Ls[row]);
        *(f4v*)(out + qb_i * 8192 + e) = acc;
    }
}

extern "C" void kernel_launch(void* const* d_in, const int* in_sizes, int n_in,
                              void* d_out, int out_size, void* d_ws, size_t ws_size,
                              hipStream_t stream) {
    const float* x  = (const float*)d_in[0];
    const float* wq = (const float*)d_in[1];
    const float* wk = (const float*)d_in[2];
    const float* wv = (const float*)d_in[3];
    float* out = (float*)d_out;

    char* ws = (char*)d_ws;
    unsigned short* xb = (unsigned short*)(ws);               // 8,388,608 B
    unsigned short* wb = (unsigned short*)(ws + 8388608);     // 196,608 B
    unsigned short* qb = (unsigned short*)(ws + 8585216);     // 1,048,576 B
    unsigned short* kb = (unsigned short*)(ws + 9633792);     // 1,048,576 B
    unsigned short* vt = (unsigned short*)(ws + 10682368);    // 1,048,576 B (V^T [64][8192])
    float* O_part = (float*)(ws + 11730944);                  // 544*8192*4 = 17,825,792 B
    float* l_part = (float*)(ws + 29556736);                  // 544*128*4 = 278,528 B
    // total ws: 29,835,264 B

    cast_kernel<<<4192, 256, 0, stream>>>(x, wq, wk, wv, xb, wb);
    proj_kernel<<<128, 256, 0, stream>>>(xb, wb, qb, kb, vt);
    attn_kernel<<<dim3(16, 64), 256, 0, stream>>>(qb, kb, vt, O_part, l_part);
    attn_reduce_kernel<<<256, 256, 0, stream>>>(O_part, l_part, out);
}